// Round 16
// baseline (1576.169 us; speedup 1.0000x reference)
//
#include <hip/hip_runtime.h>
#include <hip/hip_bf16.h>

#define T_SEQ 256
#define HID 512
#define G4 2048
#define ASTR 80  // padded LDS row stride (bytes) for 64B rows in GEMM kernels

typedef __attribute__((ext_vector_type(8))) short short8;
typedef __attribute__((ext_vector_type(4))) float floatx4;
typedef __attribute__((ext_vector_type(4))) int intx4;

__device__ inline unsigned short f2bf(float f) {
  union { __hip_bfloat16 h; unsigned short u; } cv;
  cv.h = __float2bfloat16(f);
  return cv.u;
}
__device__ inline float bf2f(unsigned short u) {
  union { unsigned short u; __hip_bfloat16 h; } cv;
  cv.u = u;
  return __bfloat162float(cv.h);
}
__device__ inline float fsigmoid(float x) {
  return __builtin_amdgcn_rcpf(1.0f + __expf(-x));
}
__device__ inline float ftanh(float x) {
  float e = __expf(2.0f * x);
  return 1.0f - 2.0f * __builtin_amdgcn_rcpf(e + 1.0f);
}

// barrier with LDS-only drain (publish stores must NOT be waited at barriers)
__device__ __forceinline__ void bar_lgkm() {
  asm volatile("s_waitcnt lgkmcnt(0)\n\ts_barrier" ::: "memory");
}

// ---------- transpose+convert: src [K][N] f32 -> dst [N][Kpad] bf16 (zero pad) ----------
__global__ __launch_bounds__(256) void transpose_bf16(const float* __restrict__ src,
                                                      unsigned short* __restrict__ dst,
                                                      int K, int N, int Kpad) {
  __shared__ float tile[32][33];
  int n0 = blockIdx.x * 32, k0 = blockIdx.y * 32;
  int tx = threadIdx.x & 31, ty = threadIdx.x >> 5;  // 32 x 8
#pragma unroll
  for (int i = 0; i < 32; i += 8) {
    int k = k0 + ty + i, n = n0 + tx;
    tile[ty + i][tx] = (k < K) ? src[(size_t)k * N + n] : 0.0f;
  }
  __syncthreads();
#pragma unroll
  for (int i = 0; i < 32; i += 8) {
    int n = n0 + ty + i, k = k0 + tx;
    dst[(size_t)n * Kpad + k] = f2bf(tile[tx][ty + i]);
  }
}

// ---------- xg1 GEMM: gather each emb row ONCE into LDS, loop over all N ----------
__global__ __launch_bounds__(256) void gemm_xg1(const float* __restrict__ emb,
                                                const int* __restrict__ wid,
                                                const int* __restrict__ pred,
                                                const unsigned short* __restrict__ Bt,
                                                unsigned short* __restrict__ C) {
  int m0 = blockIdx.x * 64;
  int tid = threadIdx.x, lane = tid & 63, w = tid >> 6;
  __shared__ __align__(16) short As[64][328];
  __shared__ __align__(16) short Bs[2][64][40];
  {
    int grow = tid >> 2, gpart = tid & 3;
    int wrow = wid[m0 + grow];
    float pflag = (float)pred[m0 + grow];
    const float* erow = emb + (size_t)wrow * 300;
#pragma unroll
    for (int i = 0; i < 10; i++) {
      int c0 = gpart * 80 + i * 8;
      float f[8];
      if (c0 + 8 <= 300) {
        float4 x0 = *(const float4*)(erow + c0);
        float4 x1 = *(const float4*)(erow + c0 + 4);
        f[0] = x0.x; f[1] = x0.y; f[2] = x0.z; f[3] = x0.w;
        f[4] = x1.x; f[5] = x1.y; f[6] = x1.z; f[7] = x1.w;
      } else {
#pragma unroll
        for (int j = 0; j < 8; j++) {
          int k = c0 + j;
          f[j] = (k < 300) ? erow[k] : ((k == 300) ? pflag : 0.0f);
        }
      }
      short8 v;
#pragma unroll
      for (int j = 0; j < 8; j++) v[j] = (short)f2bf(f[j]);
      *(short8*)&As[grow][c0] = v;
    }
  }
  int brow = tid >> 2, bpart = tid & 3;
  for (int n0 = 0; n0 < 2048; n0 += 64) {
    *(short8*)&Bs[0][brow][bpart * 8] =
        *(const short8*)(Bt + (size_t)(n0 + brow) * 320 + bpart * 8);
    bar_lgkm();
    floatx4 acc[4];
#pragma unroll
    for (int i = 0; i < 4; i++) acc[i] = (floatx4){0.f, 0.f, 0.f, 0.f};
#pragma unroll
    for (int ks = 0; ks < 10; ks++) {
      if (ks < 9)
        *(short8*)&Bs[(ks + 1) & 1][brow][bpart * 8] =
            *(const short8*)(Bt + (size_t)(n0 + brow) * 320 + (ks + 1) * 32 + bpart * 8);
      short8 afr = *(const short8*)&As[w * 16 + (lane & 15)][ks * 32 + (lane >> 4) * 8];
#pragma unroll
      for (int nc = 0; nc < 4; nc++) {
        short8 bfr = *(const short8*)&Bs[ks & 1][nc * 16 + (lane & 15)][(lane >> 4) * 8];
        acc[nc] = __builtin_amdgcn_mfma_f32_16x16x32_bf16(afr, bfr, acc[nc], 0, 0, 0);
      }
      bar_lgkm();
    }
#pragma unroll
    for (int nc = 0; nc < 4; nc++)
#pragma unroll
      for (int r = 0; r < 4; r++) {
        int rr = m0 + w * 16 + ((lane >> 4) << 2) + r;
        int cc = n0 + nc * 16 + (lane & 15);
        C[(size_t)rr * G4 + cc] = f2bf(acc[nc][r]);
      }
  }
}

// ---------- tagged exchange (IC-only sc0sc1, no-allocate: r8 lesson) ----------
// Thread owns 32 cols of one 512-col row: granule i (0..7) = 4 tagged u32 at cols
// 8*c16 + 128*(i>>1) + 4*(i&1). Valid when all 4 high-16 tags == want.
__device__ __forceinline__ void stg_issue(const unsigned int* rowbase, int c16,
                                          intx4 (&v)[8], unsigned done) {
#pragma unroll
  for (int i = 0; i < 8; i++) {
    if (!(done & (1u << i))) {
      const unsigned int* p = rowbase + 8 * c16 + 128 * (i >> 1) + 4 * (i & 1);
      asm volatile("global_load_dwordx4 %0, %1, off sc0 sc1" : "=v"(v[i]) : "v"(p) : "memory");
    }
  }
}
__device__ __forceinline__ void stg_check(unsigned want, char* AhRow, int sw, int c16,
                                          intx4 (&v)[8], unsigned& done) {
  asm volatile("s_waitcnt vmcnt(0)" ::: "memory");
#pragma unroll
  for (int i = 0; i < 8; i++) {
    if (!(done & (1u << i))) {
      intx4 a = v[i];
      unsigned u0 = (unsigned)a.x, u1 = (unsigned)a.y, u2 = (unsigned)a.z, u3 = (unsigned)a.w;
      bool ok = ((u0 >> 16) == want) & ((u1 >> 16) == want) & ((u2 >> 16) == want) &
                ((u3 >> 16) == want);
      if (ok) {
        uint2 pp;
        pp.x = (u0 & 0xffffu) | (u1 << 16);
        pp.y = (u2 & 0xffffu) | (u3 << 16);
        int s = c16 + 16 * (i >> 1);
        *(uint2*)(AhRow + ((s * 16) ^ sw) + (i & 1) * 8) = pp;
        done |= (1u << i);
      }
    }
  }
}
__device__ __forceinline__ void stg_finish(const unsigned int* rowbase, unsigned want,
                                           char* AhRow, int sw, int c16,
                                           intx4 (&v)[8], unsigned& done) {
  stg_check(want, AhRow, sw, c16, v, done);
  while (done != 0xFFu) {
    __builtin_amdgcn_s_sleep(1);
    stg_issue(rowbase, c16, v, done);
    stg_check(want, AhRow, sw, c16, v, done);
  }
}

// ---------- merged persistent dual-layer masked LSTM: 256 blocks x 256 threads ----------
// r14 base (best: 1244us) + GATE COLOCATION: wave w owns ALL 4 gates of j-cols
// j0+4w..j0+4w+3 (output col c = (gate<<2)|jl). The 4 gate pre-acts of any (row,j) then
// live in the same wave, 4 lanes apart -> gathered with __shfl (no LDS, no barrier);
// activations run on 16 lanes/wave with c-state in VGPRs. Deletes both gds barriers and
// both gds LDS round-trips: 4 barriers/step -> 2 (post-stageA, post-stageB). WAR safety
// of AhA/AhB/xgt with 2 collective barriers verified (readers always arrive at the next
// barrier before writers pass it). Everything else r14-proven: IC-only tagged exchange,
// depth-2 ring (memset/launch), U1+W2 regs / U2 in LDS, issueB before chain2a,
// issueA after chain2b, waves_per_eu(1,1). pend[] shared A/B (disjoint liveness).
__global__ __launch_bounds__(256, 1) __attribute__((amdgpu_waves_per_eu(1, 1)))
void lstm_merged(
    const unsigned short* __restrict__ xg1,
    const unsigned short* __restrict__ Ut1, const float* __restrict__ b1,
    const unsigned short* __restrict__ Wt2, const unsigned short* __restrict__ Ut2,
    const float* __restrict__ b2, const int* __restrict__ wid,
    unsigned int* ex, unsigned short* h2seq) {
  const int blk = blockIdx.x;
  const int bgrp = blk & 7, jblk = blk >> 3;
  const int b0 = bgrp * 16, j0 = jblk * 16;
  const int tid = threadIdx.x, lane = tid & 63, w = tid >> 6;  // 4 waves

  __shared__ __align__(16) char AhA[16 * 1024];  // h1(t-1) bf16 [16][512], swizzled
  __shared__ __align__(16) char AhB[16 * 1024];  // h2(t-2)
  __shared__ __align__(16) char U2L[64 * 1024];  // U2 slice [64 ucols][512 k], swizzled
  __shared__ __align__(16) unsigned short xgt[4][16][16];  // [gate][row][jcol-in-block]

  const int row = tid >> 4, c16 = tid & 15;  // staging map
  const int sw = (row & 7) << 4;
  char* AhRowA = AhA + row * 1024;
  char* AhRowB = AhB + row * 1024;

  // output-col mapping: c = lane&15 -> gate = c>>2, j-in-block = 4w + (c&3)
  const int c = lane & 15;
  const int gate_c = c >> 2;
  const int jcb_c = (w << 2) | (c & 3);      // col-in-block of this lane's output col
  const int ucol = gate_c * 512 + j0 + jcb_c;

  short8 uf1[16], wf2[16];
  {
    const unsigned short* p1 = Ut1 + (size_t)ucol * 512 + ((lane >> 4) * 8);
    const unsigned short* p2 = Wt2 + (size_t)ucol * 512 + ((lane >> 4) * 8);
#pragma unroll
    for (int kk = 0; kk < 16; kk++) {
      uf1[kk] = *(const short8*)(p1 + kk * 32);
      wf2[kk] = *(const short8*)(p2 + kk * 32);
    }
  }
  // U2 slice -> LDS (64 ucols x 1024B, XOR-swizzled); row r = gate*16 + jcb
  for (int i = tid; i < 4096; i += 256) {
    int r = i >> 6, seg = i & 63;
    short8 v = *(const short8*)(Ut2 + (size_t)((r >> 4) * 512 + j0 + (r & 15)) * 512 + seg * 8);
    *(short8*)(U2L + r * 1024 + ((seg * 16) ^ ((r & 7) << 4))) = v;
  }
  {
    short8 z = {0, 0, 0, 0, 0, 0, 0, 0};
    for (int i = tid; i < 1024; i += 256) {
      *(short8*)(AhA + i * 16) = z;
      *(short8*)(AhB + i * 16) = z;
    }
  }
  __syncthreads();

  // acting-lane setup: lanes with (lane&12)==0; each handles 4 rows x 1 j
  const int jl = lane & 3;
  const bool is_act = (lane & 12) == 0;
  const int arow0 = (lane >> 4) << 2;
  const int jj = j0 + (w << 2) + jl;   // global j (0..511)
  const int jcb = (w << 2) | jl;       // col-in-block (0..15)
  float b1a[4], b2a[4];
#pragma unroll
  for (int g = 0; g < 4; g++) {
    b1a[g] = b1[g * 512 + jj];
    b2a[g] = b2[g * 512 + jj];
  }
  float cst1a[4] = {0.f, 0.f, 0.f, 0.f};
  float cst2a[4] = {0.f, 0.f, 0.f, 0.f};
  int mca[4], mpa[4];
#pragma unroll
  for (int r = 0; r < 4; r++) {
    mca[r] = is_act ? wid[(size_t)(b0 + arow0 + r) * T_SEQ] : 0;
    mpa[r] = 0;
  }

  // xgt staging (r14 pattern): thread stages uint2 = 4 bf16 per step
  int xg_g = tid >> 6, xg_rw = (tid >> 2) & 15, xg_part = tid & 3;
  uint2 xpf = *(const uint2*)(xg1 + ((size_t)(b0 + xg_rw) * T_SEQ + 0) * G4 + xg_g * 512 + j0 +
                              xg_part * 4);

  const size_t SLOT = (size_t)2 * 128 * 512;  // u32 per ring slot
  const int frow = lane & 15, kbase = (lane >> 4) * 16, fsw = (frow & 7) << 4;
  const int urow = gate_c * 16 + jcb_c;  // U2L row for this lane's output col
  const int usw = (urow & 7) << 4;

  intx4 pend[8];           // shared stage-A / stage-B buffer (disjoint liveness)
  unsigned doneA = 0xFFu;  // nothing staged for t=0

  for (int t = 0; t <= T_SEQ; t++) {
    // ---- finish stage A: h1(t-1) (issued after chain2b of previous iteration) ----
    if (t > 0) {
      const unsigned int* bA = ex + (size_t)((t - 1) & 1) * SLOT + (size_t)(b0 + row) * 512;
      stg_finish(bA, (unsigned)t, AhRowA, sw, c16, pend, doneA);
    }
    if (t < T_SEQ) {
      *(uint2*)(&xgt[xg_g][xg_rw][xg_part * 4]) = xpf;
      if (t + 1 < T_SEQ)
        xpf = *(const uint2*)(xg1 + ((size_t)(b0 + xg_rw) * T_SEQ + (t + 1)) * G4 + xg_g * 512 +
                              j0 + xg_part * 4);
    }
    // prefetch next-step masks (acting lanes)
    int mna[4];
#pragma unroll
    for (int r = 0; r < 4; r++)
      mna[r] = (is_act && t + 1 < T_SEQ) ? wid[(size_t)(b0 + arow0 + r) * T_SEQ + t + 1] : 0;
    bar_lgkm();  // (1) AhA + xgt visible

    // ---- layer1 chain: U1 over AhA, 2 interleaved accumulators ----
    floatx4 a1x = (floatx4){0.f, 0.f, 0.f, 0.f};
    floatx4 a1y = (floatx4){0.f, 0.f, 0.f, 0.f};
#pragma unroll
    for (int kk = 0; kk < 16; kk += 2) {
      short8 a0 = *(const short8*)(AhA + frow * 1024 + ((kk * 64 + kbase) ^ fsw));
      short8 a1f = *(const short8*)(AhA + frow * 1024 + (((kk + 1) * 64 + kbase) ^ fsw));
      a1x = __builtin_amdgcn_mfma_f32_16x16x32_bf16(a0, uf1[kk], a1x, 0, 0, 0);
      a1y = __builtin_amdgcn_mfma_f32_16x16x32_bf16(a1f, uf1[kk + 1], a1y, 0, 0, 0);
    }

    // ---- act1 via in-wave shuffles (no barrier) + publish h1(t) ----
    if (t < T_SEQ) {
      float gv[4][4];  // [gate][r]
#pragma unroll
      for (int r = 0; r < 4; r++) {
        float av = a1x[r] + a1y[r];
#pragma unroll
        for (int g = 0; g < 4; g++)
          gv[g][r] = __shfl(av, (lane & 48) | (g << 2) | jl);
      }
      if (is_act) {
#pragma unroll
        for (int r = 0; r < 4; r++) {
          int ar = arow0 + r;
          float gi = gv[0][r] + b1a[0] + bf2f(xgt[0][ar][jcb]);
          float gf = gv[1][r] + b1a[1] + bf2f(xgt[1][ar][jcb]);
          float gc = gv[2][r] + b1a[2] + bf2f(xgt[2][ar][jcb]);
          float go = gv[3][r] + b1a[3] + bf2f(xgt[3][ar][jcb]);
          float iv = fsigmoid(gi), fv = fsigmoid(gf), cd = ftanh(gc), ov = fsigmoid(go);
          float cold = cst1a[r];
          float cn = fv * cold + iv * cd;
          float hn = ov * ftanh(cn);
          if (mca[r] == 0) {
            cn = cold;
            hn = bf2f(*(const unsigned short*)(AhA + ar * 1024 + ((jj * 2) ^ ((ar & 7) << 4))));
          }
          cst1a[r] = cn;
          unsigned v1 = (((unsigned)(t + 1)) << 16) | f2bf(hn);
          unsigned int* d1 = ex + (size_t)(t & 1) * SLOT + (size_t)(b0 + ar) * 512 + jj;
          asm volatile("global_store_dword %0, %1, off sc0 sc1" ::"v"(d1), "v"(v1) : "memory");
        }
      }
    }
    if (t == 0 && is_act) {  // h2(-1)=0, tag 1, slot 0 (layer2 bootstrap)
#pragma unroll
      for (int r = 0; r < 4; r++) {
        unsigned v2 = 1u << 16;
        unsigned int* d2 = ex + (size_t)128 * 512 + (size_t)(b0 + arow0 + r) * 512 + jj;
        asm volatile("global_store_dword %0, %1, off sc0 sc1" ::"v"(d2), "v"(v2) : "memory");
      }
    }

    // ---- layer2 (step t-1): W2 chain over AhA; h2 stage issued around it ----
    if (t > 0) {
      unsigned doneB = 0;
      const unsigned int* bB = ex + (size_t)((t - 1) & 1) * SLOT + (size_t)128 * 512 +
                               (size_t)(b0 + row) * 512;
      stg_issue(bB, c16, pend, doneB);  // h2(t-2) loads fly during W2 chain

      floatx4 a2x = (floatx4){0.f, 0.f, 0.f, 0.f};
      floatx4 a2y = (floatx4){0.f, 0.f, 0.f, 0.f};
#pragma unroll
      for (int kk = 0; kk < 16; kk += 2) {
        short8 a0 = *(const short8*)(AhA + frow * 1024 + ((kk * 64 + kbase) ^ fsw));
        short8 a1f = *(const short8*)(AhA + frow * 1024 + (((kk + 1) * 64 + kbase) ^ fsw));
        a2x = __builtin_amdgcn_mfma_f32_16x16x32_bf16(a0, wf2[kk], a2x, 0, 0, 0);
        a2y = __builtin_amdgcn_mfma_f32_16x16x32_bf16(a1f, wf2[kk + 1], a2y, 0, 0, 0);
      }

      stg_finish(bB, (unsigned)t, AhRowB, sw, c16, pend, doneB);
      bar_lgkm();  // (2) AhB visible

      // chain2b: U2 fragments from LDS
#pragma unroll
      for (int kk = 0; kk < 16; kk += 2) {
        short8 a0 = *(const short8*)(AhB + frow * 1024 + ((kk * 64 + kbase) ^ fsw));
        short8 u0 = *(const short8*)(U2L + urow * 1024 + ((kk * 64 + kbase) ^ usw));
        short8 a1f = *(const short8*)(AhB + frow * 1024 + (((kk + 1) * 64 + kbase) ^ fsw));
        short8 u1 = *(const short8*)(U2L + urow * 1024 + (((kk + 1) * 64 + kbase) ^ usw));
        a2x = __builtin_amdgcn_mfma_f32_16x16x32_bf16(a0, u0, a2x, 0, 0, 0);
        a2y = __builtin_amdgcn_mfma_f32_16x16x32_bf16(a1f, u1, a2y, 0, 0, 0);
      }

      // issue stage A for t+1 (r14-proven placement: peers' act1 publish ~committed)
      if (t < T_SEQ) {
        const unsigned int* nA = ex + (size_t)(t & 1) * SLOT + (size_t)(b0 + row) * 512;
        doneA = 0;
        stg_issue(nA, c16, pend, doneA);
      }

      // act2 via shuffles + publish h2(t-1) + h2seq
      {
        float gv[4][4];
#pragma unroll
        for (int r = 0; r < 4; r++) {
          float av = a2x[r] + a2y[r];
#pragma unroll
          for (int g = 0; g < 4; g++)
            gv[g][r] = __shfl(av, (lane & 48) | (g << 2) | jl);
        }
        if (is_act) {
#pragma unroll
          for (int r = 0; r < 4; r++) {
            int ar = arow0 + r;
            float gi = gv[0][r] + b2a[0];
            float gf = gv[1][r] + b2a[1];
            float gc = gv[2][r] + b2a[2];
            float go = gv[3][r] + b2a[3];
            float iv = fsigmoid(gi), fv = fsigmoid(gf), cd = ftanh(gc), ov = fsigmoid(go);
            float cold = cst2a[r];
            float cn = fv * cold + iv * cd;
            float hn = ov * ftanh(cn);
            if (mpa[r] == 0) {
              cn = cold;
              hn = bf2f(*(const unsigned short*)(AhB + ar * 1024 + ((jj * 2) ^ ((ar & 7) << 4))));
            }
            cst2a[r] = cn;
            unsigned short hb = f2bf(hn);
            if (t < T_SEQ) {
              unsigned v2 = (((unsigned)(t + 1)) << 16) | hb;
              unsigned int* d2 = ex + (size_t)(t & 1) * SLOT + (size_t)128 * 512 +
                                 (size_t)(b0 + ar) * 512 + jj;
              asm volatile("global_store_dword %0, %1, off sc0 sc1" ::"v"(d2), "v"(v2)
                           : "memory");
            }
            h2seq[((size_t)(b0 + ar) * T_SEQ + (t - 1)) * HID + jj] = hb;
          }
        }
      }
    } else {
      // t == 0: issue stage A for t=1 at iteration end (step-0-only)
      const unsigned int* nA = ex + (size_t)(t & 1) * SLOT + (size_t)(b0 + row) * 512;
      doneA = 0;
      stg_issue(nA, c16, pend, doneA);
    }
#pragma unroll
    for (int r = 0; r < 4; r++) {
      mpa[r] = mca[r];
      mca[r] = mna[r];
    }
  }
}

// ---------- dense (512->96) + softmax, MFMA ----------
__global__ __launch_bounds__(256) void dense_softmax(const unsigned short* __restrict__ h2,
                                                     const unsigned short* __restrict__ Wdt,
                                                     const float* __restrict__ bd,
                                                     float* __restrict__ out) {
  int m0 = blockIdx.x * 64;
  int tid = threadIdx.x, lane = tid & 63, w = tid >> 6;
  __shared__ __align__(16) char As[64 * ASTR];
  __shared__ __align__(16) char Bs[96 * ASTR];
  floatx4 acc[6];
#pragma unroll
  for (int i = 0; i < 6; i++) acc[i] = (floatx4){0.f, 0.f, 0.f, 0.f};
  for (int k0 = 0; k0 < 512; k0 += 32) {
    {
      int row = tid >> 2, part = tid & 3;
      short8 v = *(const short8*)(h2 + (size_t)(m0 + row) * 512 + k0 + part * 8);
      *(short8*)(As + row * ASTR + part * 16) = v;
    }
    for (int u = tid; u < 96 * 4; u += 256) {
      int col = u >> 2, part = u & 3;
      short8 v = *(const short8*)(Wdt + (size_t)col * 512 + k0 + part * 8);
      *(short8*)(Bs + col * ASTR + part * 16) = v;
    }
    __syncthreads();
    int arow = w * 16 + (lane & 15);
    short8 a = *(const short8*)(As + arow * ASTR + (lane >> 4) * 16);
#pragma unroll
    for (int nc = 0; nc < 6; nc++) {
      int bcol = nc * 16 + (lane & 15);
      short8 b = *(const short8*)(Bs + bcol * ASTR + (lane >> 4) * 16);
      acc[nc] = __builtin_amdgcn_mfma_f32_16x16x32_bf16(a, b, acc[nc], 0, 0, 0);
    }
    __syncthreads();
  }
  float bv[6];
#pragma unroll
  for (int nc = 0; nc < 6; nc++) bv[nc] = bd[nc * 16 + (lane & 15)];
#pragma unroll
  for (int r = 0; r < 4; r++) {
    float v[6];
    float mx = -1e30f;
#pragma unroll
    for (int nc = 0; nc < 6; nc++) {
      v[nc] = acc[nc][r] + bv[nc];
      mx = fmaxf(mx, v[nc]);
    }
#pragma unroll
    for (int d = 1; d < 16; d <<= 1) mx = fmaxf(mx, __shfl_xor(mx, d));
    float s = 0.f;
#pragma unroll
    for (int nc = 0; nc < 6; nc++) {
      v[nc] = __expf(v[nc] - mx);
      s += v[nc];
    }
#pragma unroll
    for (int d = 1; d < 16; d <<= 1) s += __shfl_xor(s, d);
    float inv = 1.0f / s;
    int rr = m0 + w * 16 + ((lane >> 4) << 2) + r;
#pragma unroll
    for (int nc = 0; nc < 6; nc++) out[(size_t)rr * 96 + nc * 16 + (lane & 15)] = v[nc] * inv;
  }
}

extern "C" void kernel_launch(void* const* d_in, const int* in_sizes, int n_in,
                              void* d_out, int out_size, void* d_ws, size_t ws_size,
                              hipStream_t stream) {
  (void)in_sizes; (void)n_in; (void)out_size; (void)ws_size;
  const int* word_ids = (const int*)d_in[0];
  const int* pred = (const int*)d_in[1];
  const float* emb = (const float*)d_in[2];
  const float* W1 = (const float*)d_in[3];
  const float* U1 = (const float*)d_in[4];
  const float* b1 = (const float*)d_in[5];
  const float* W2 = (const float*)d_in[6];
  const float* U2 = (const float*)d_in[7];
  const float* b2 = (const float*)d_in[8];
  const float* Wd = (const float*)d_in[9];
  const float* bd = (const float*)d_in[10];
  float* out = (float*)d_out;

  const size_t EXBYTES = (size_t)2 * 2 * 128 * 512 * 4;  // 1 MB depth-2 ring

  char* p = (char*)d_ws;
  unsigned short* xg = (unsigned short*)p;   p += (size_t)32768 * 2048 * 2;  // 128MB
  unsigned short* h2s = (unsigned short*)p;  p += (size_t)32768 * 512 * 2;   // 32MB
  unsigned int* ex = (unsigned int*)p;       p += EXBYTES;
  unsigned short* Ut1 = (unsigned short*)p;  p += (size_t)2048 * 512 * 2;
  unsigned short* Ut2 = (unsigned short*)p;  p += (size_t)2048 * 512 * 2;
  unsigned short* Wt1 = (unsigned short*)p;  p += (size_t)2048 * 320 * 2;
  unsigned short* Wt2 = (unsigned short*)p;  p += (size_t)2048 * 512 * 2;
  unsigned short* Wdt = (unsigned short*)p;  p += (size_t)96 * 512 * 2;

  // clear exchange ring every launch: kills cross-replay stale-tag race
  hipMemsetAsync(ex, 0, EXBYTES, stream);

  hipLaunchKernelGGL(transpose_bf16, dim3(64, 16), dim3(256), 0, stream, U1, Ut1, 512, 2048, 512);
  hipLaunchKernelGGL(transpose_bf16, dim3(64, 16), dim3(256), 0, stream, U2, Ut2, 512, 2048, 512);
  hipLaunchKernelGGL(transpose_bf16, dim3(64, 10), dim3(256), 0, stream, W1, Wt1, 301, 2048, 320);
  hipLaunchKernelGGL(transpose_bf16, dim3(64, 16), dim3(256), 0, stream, W2, Wt2, 512, 2048, 512);
  hipLaunchKernelGGL(transpose_bf16, dim3(3, 16), dim3(256), 0, stream, Wd, Wdt, 512, 96, 512);

  hipLaunchKernelGGL(gemm_xg1, dim3(512), dim3(256), 0, stream,
                     emb, word_ids, pred, Wt1, xg);
  hipLaunchKernelGGL(lstm_merged, dim3(256), dim3(256), 0, stream,
                     xg, Ut1, b1, Wt2, Ut2, b2, word_ids, ex, h2s);
  hipLaunchKernelGGL(dense_softmax, dim3(512), dim3(256), 0, stream, h2s, Wdt, bd, out);
}

// Round 17
// 1364.030 us; speedup vs baseline: 1.1555x; 1.1555x over previous
//
#include <hip/hip_runtime.h>
#include <hip/hip_bf16.h>

#define T_SEQ 256
#define HID 512
#define G4 2048
#define ASTR 80  // padded LDS row stride (bytes) for 64B rows in GEMM kernels

typedef __attribute__((ext_vector_type(8))) short short8;
typedef __attribute__((ext_vector_type(4))) float floatx4;
typedef __attribute__((ext_vector_type(4))) int intx4;

__device__ inline unsigned short f2bf(float f) {
  union { __hip_bfloat16 h; unsigned short u; } cv;
  cv.h = __float2bfloat16(f);
  return cv.u;
}
__device__ inline float bf2f(unsigned short u) {
  union { unsigned short u; __hip_bfloat16 h; } cv;
  cv.u = u;
  return __bfloat162float(cv.h);
}
__device__ inline float fsigmoid(float x) {
  return __builtin_amdgcn_rcpf(1.0f + __expf(-x));
}
__device__ inline float ftanh(float x) {
  float e = __expf(2.0f * x);
  return 1.0f - 2.0f * __builtin_amdgcn_rcpf(e + 1.0f);
}

// barrier with LDS-only drain (publish stores must NOT be waited at barriers)
__device__ __forceinline__ void bar_lgkm() {
  asm volatile("s_waitcnt lgkmcnt(0)\n\ts_barrier" ::: "memory");
}

// ---------- transpose+convert: src [K][N] f32 -> dst [N][Kpad] bf16 (zero pad) ----------
__global__ __launch_bounds__(256) void transpose_bf16(const float* __restrict__ src,
                                                      unsigned short* __restrict__ dst,
                                                      int K, int N, int Kpad) {
  __shared__ float tile[32][33];
  int n0 = blockIdx.x * 32, k0 = blockIdx.y * 32;
  int tx = threadIdx.x & 31, ty = threadIdx.x >> 5;  // 32 x 8
#pragma unroll
  for (int i = 0; i < 32; i += 8) {
    int k = k0 + ty + i, n = n0 + tx;
    tile[ty + i][tx] = (k < K) ? src[(size_t)k * N + n] : 0.0f;
  }
  __syncthreads();
#pragma unroll
  for (int i = 0; i < 32; i += 8) {
    int n = n0 + ty + i, k = k0 + tx;
    dst[(size_t)n * Kpad + k] = f2bf(tile[tx][ty + i]);
  }
}

// ---------- xg1 GEMM: gather each emb row ONCE into LDS, loop over all N ----------
__global__ __launch_bounds__(256) void gemm_xg1(const float* __restrict__ emb,
                                                const int* __restrict__ wid,
                                                const int* __restrict__ pred,
                                                const unsigned short* __restrict__ Bt,
                                                unsigned short* __restrict__ C) {
  int m0 = blockIdx.x * 64;
  int tid = threadIdx.x, lane = tid & 63, w = tid >> 6;
  __shared__ __align__(16) short As[64][328];
  __shared__ __align__(16) short Bs[2][64][40];
  {
    int grow = tid >> 2, gpart = tid & 3;
    int wrow = wid[m0 + grow];
    float pflag = (float)pred[m0 + grow];
    const float* erow = emb + (size_t)wrow * 300;
#pragma unroll
    for (int i = 0; i < 10; i++) {
      int c0 = gpart * 80 + i * 8;
      float f[8];
      if (c0 + 8 <= 300) {
        float4 x0 = *(const float4*)(erow + c0);
        float4 x1 = *(const float4*)(erow + c0 + 4);
        f[0] = x0.x; f[1] = x0.y; f[2] = x0.z; f[3] = x0.w;
        f[4] = x1.x; f[5] = x1.y; f[6] = x1.z; f[7] = x1.w;
      } else {
#pragma unroll
        for (int j = 0; j < 8; j++) {
          int k = c0 + j;
          f[j] = (k < 300) ? erow[k] : ((k == 300) ? pflag : 0.0f);
        }
      }
      short8 v;
#pragma unroll
      for (int j = 0; j < 8; j++) v[j] = (short)f2bf(f[j]);
      *(short8*)&As[grow][c0] = v;
    }
  }
  int brow = tid >> 2, bpart = tid & 3;
  for (int n0 = 0; n0 < 2048; n0 += 64) {
    *(short8*)&Bs[0][brow][bpart * 8] =
        *(const short8*)(Bt + (size_t)(n0 + brow) * 320 + bpart * 8);
    bar_lgkm();
    floatx4 acc[4];
#pragma unroll
    for (int i = 0; i < 4; i++) acc[i] = (floatx4){0.f, 0.f, 0.f, 0.f};
#pragma unroll
    for (int ks = 0; ks < 10; ks++) {
      if (ks < 9)
        *(short8*)&Bs[(ks + 1) & 1][brow][bpart * 8] =
            *(const short8*)(Bt + (size_t)(n0 + brow) * 320 + (ks + 1) * 32 + bpart * 8);
      short8 afr = *(const short8*)&As[w * 16 + (lane & 15)][ks * 32 + (lane >> 4) * 8];
#pragma unroll
      for (int nc = 0; nc < 4; nc++) {
        short8 bfr = *(const short8*)&Bs[ks & 1][nc * 16 + (lane & 15)][(lane >> 4) * 8];
        acc[nc] = __builtin_amdgcn_mfma_f32_16x16x32_bf16(afr, bfr, acc[nc], 0, 0, 0);
      }
      bar_lgkm();
    }
#pragma unroll
    for (int nc = 0; nc < 4; nc++)
#pragma unroll
      for (int r = 0; r < 4; r++) {
        int rr = m0 + w * 16 + ((lane >> 4) << 2) + r;
        int cc = n0 + nc * 16 + (lane & 15);
        C[(size_t)rr * G4 + cc] = f2bf(acc[nc][r]);
      }
  }
}

// ---------- tagged exchange (IC-only: sc0 sc1 is no-allocate; NEVER poll via L2 -
// stale allocated lines are not invalidated cross-XCD -> r8 hang) ----------
// Thread owns 32 cols of one 512-col row: granule i (0..7) = 4 tagged u32 at cols
// 8*c16 + 128*(i>>1) + 4*(i&1). Valid when all 4 high-16 tags == want.
__device__ __forceinline__ void stg_issue(const unsigned int* rowbase, int c16,
                                          intx4 (&v)[8], unsigned done) {
#pragma unroll
  for (int i = 0; i < 8; i++) {
    if (!(done & (1u << i))) {
      const unsigned int* p = rowbase + 8 * c16 + 128 * (i >> 1) + 4 * (i & 1);
      asm volatile("global_load_dwordx4 %0, %1, off sc0 sc1" : "=v"(v[i]) : "v"(p) : "memory");
    }
  }
}
__device__ __forceinline__ void stg_check(unsigned want, char* AhRow, int sw, int c16,
                                          intx4 (&v)[8], unsigned& done) {
  asm volatile("s_waitcnt vmcnt(0)" ::: "memory");
#pragma unroll
  for (int i = 0; i < 8; i++) {
    if (!(done & (1u << i))) {
      intx4 a = v[i];
      unsigned u0 = (unsigned)a.x, u1 = (unsigned)a.y, u2 = (unsigned)a.z, u3 = (unsigned)a.w;
      bool ok = ((u0 >> 16) == want) & ((u1 >> 16) == want) & ((u2 >> 16) == want) &
                ((u3 >> 16) == want);
      if (ok) {
        uint2 pp;
        pp.x = (u0 & 0xffffu) | (u1 << 16);
        pp.y = (u2 & 0xffffu) | (u3 << 16);
        int s = c16 + 16 * (i >> 1);
        *(uint2*)(AhRow + ((s * 16) ^ sw) + (i & 1) * 8) = pp;
        done |= (1u << i);
      }
    }
  }
}
__device__ __forceinline__ void stg_finish(const unsigned int* rowbase, unsigned want,
                                           char* AhRow, int sw, int c16,
                                           intx4 (&v)[8], unsigned& done) {
  stg_check(want, AhRow, sw, c16, v, done);
  while (done != 0xFFu) {
    __builtin_amdgcn_s_sleep(1);
    stg_issue(rowbase, c16, v, done);
    stg_check(want, AhRow, sw, c16, v, done);
  }
}

// ---------- merged persistent dual-layer masked LSTM: 256 blocks x 256 threads ----------
// r14 == empirical optimum (lstm 1244us). Schedule:
//  - stage-A(t+1) issued right after chain2b's gds store (peers' act1 publish committed
//    ~700-1000cy earlier; act2+publish covers the RT). r13's earlier issue = premature.
//  - stage-B issued before chain2a, finished after it.
//  - U1+W2 register-resident (128 VGPR), U2 in LDS (XOR-swizzled), waves_per_eu(1,1).
//  - IC-only (sc0 sc1, no-allocate) tagged exchange; depth-2 ring; memset per launch.
// Residual ~8000cy/step is inter-block skew (max over 32 producers, twice per step):
// r15 (flag+L2 broadcast) cut traffic but was flat; r16 (gate colocation) lost on
// store coalescing + shfl VALU. This structure is the fixed point.
__global__ __launch_bounds__(256, 1) __attribute__((amdgpu_waves_per_eu(1, 1)))
void lstm_merged(
    const unsigned short* __restrict__ xg1,
    const unsigned short* __restrict__ Ut1, const float* __restrict__ b1,
    const unsigned short* __restrict__ Wt2, const unsigned short* __restrict__ Ut2,
    const float* __restrict__ b2, const int* __restrict__ wid,
    unsigned int* ex, unsigned short* h2seq) {
  const int blk = blockIdx.x;
  const int bgrp = blk & 7, jblk = blk >> 3;
  const int b0 = bgrp * 16, j0 = jblk * 16;
  const int tid = threadIdx.x, lane = tid & 63, w = tid >> 6;  // 4 waves = 4 gates

  __shared__ __align__(16) char AhA[16 * 1024];  // h1(t-1) bf16 [16][512], swizzled
  __shared__ __align__(16) char AhB[16 * 1024];  // h2(t-2)
  __shared__ __align__(16) char U2L[64 * 1024];  // U2 slice [64 ucols][512 k], swizzled
  __shared__ float gds[4][16][16];               // gate pre-acts, reused by both layers
  __shared__ float cst1[16][16];
  __shared__ float cst2[16][16];

  const int row = tid >> 4, c16 = tid & 15;  // act + stage mapping
  const int sw = (row & 7) << 4;
  char* AhRowA = AhA + row * 1024;
  char* AhRowB = AhB + row * 1024;
  const int ucol = w * 512 + j0 + (lane & 15);
  const int* widp = wid + (size_t)(b0 + row) * T_SEQ;

  // register weights: U1 + W2 only (128 VGPR); U2 lives in LDS
  short8 uf1[16], wf2[16];
  {
    const unsigned short* p1 = Ut1 + (size_t)ucol * 512 + ((lane >> 4) * 8);
    const unsigned short* p2 = Wt2 + (size_t)ucol * 512 + ((lane >> 4) * 8);
#pragma unroll
    for (int kk = 0; kk < 16; kk++) {
      uf1[kk] = *(const short8*)(p1 + kk * 32);
      wf2[kk] = *(const short8*)(p2 + kk * 32);
    }
  }
  // U2 slice -> LDS (64 rows x 1024B, XOR-swizzled like Ah tiles)
  for (int i = tid; i < 4096; i += 256) {
    int r = i >> 6, seg = i & 63;
    short8 v = *(const short8*)(Ut2 + (size_t)((r >> 4) * 512 + j0 + (r & 15)) * 512 + seg * 8);
    *(short8*)(U2L + r * 1024 + ((seg * 16) ^ ((r & 7) << 4))) = v;
  }
  float b1v[4], b2v[4];
#pragma unroll
  for (int g = 0; g < 4; g++) {
    b1v[g] = b1[g * 512 + j0 + c16];
    b2v[g] = b2[g * 512 + j0 + c16];
  }
  cst1[row][c16] = 0.0f;
  cst2[row][c16] = 0.0f;
  {
    short8 z = {0, 0, 0, 0, 0, 0, 0, 0};
    for (int i = tid; i < 1024; i += 256) {
      *(short8*)(AhA + i * 16) = z;
      *(short8*)(AhB + i * 16) = z;
    }
  }
  __syncthreads();

  const unsigned short* xgrow = xg1 + (size_t)(b0 + row) * T_SEQ * G4 + j0 + c16;
  unsigned short xc[4], xn[4];
#pragma unroll
  for (int g = 0; g < 4; g++) { xc[g] = xgrow[g * 512]; xn[g] = 0; }
  int mcur = widp[0];
  int mprev = 0;

  const size_t SLOT = (size_t)2 * 128 * 512;  // u32 per ring slot
  const int frow = lane & 15, kbase = (lane >> 4) * 16, fsw = (frow & 7) << 4;
  const int urow = w * 16 + (lane & 15);
  const int usw = (urow & 7) << 4;

  intx4 pendA[8], pendB[8];
  unsigned doneA = 0xFFu;  // nothing staged for t=0

  for (int t = 0; t <= T_SEQ; t++) {
    // ---- finish stage A: h1(t-1) ----
    if (t > 0) {
      const unsigned int* bA = ex + (size_t)((t - 1) & 1) * SLOT + (size_t)(b0 + row) * 512;
      stg_finish(bA, (unsigned)t, AhRowA, sw, c16, pendA, doneA);
    }
    // prefetch next step's xg (plain cached loads)
    if (t + 1 < T_SEQ) {
      const unsigned short* xr = xgrow + (size_t)(t + 1) * G4;
#pragma unroll
      for (int g = 0; g < 4; g++) xn[g] = xr[g * 512];
    }
    bar_lgkm();  // (1) AhA staged & visible

    // ---- layer1 chain: U1 over AhA, 2 interleaved accumulators ----
    floatx4 a1x = (floatx4){0.f, 0.f, 0.f, 0.f};
    floatx4 a1y = (floatx4){0.f, 0.f, 0.f, 0.f};
#pragma unroll
    for (int kk = 0; kk < 16; kk += 2) {
      short8 a0 = *(const short8*)(AhA + frow * 1024 + ((kk * 64 + kbase) ^ fsw));
      short8 a1f = *(const short8*)(AhA + frow * 1024 + (((kk + 1) * 64 + kbase) ^ fsw));
      a1x = __builtin_amdgcn_mfma_f32_16x16x32_bf16(a0, uf1[kk], a1x, 0, 0, 0);
      a1y = __builtin_amdgcn_mfma_f32_16x16x32_bf16(a1f, uf1[kk + 1], a1y, 0, 0, 0);
    }
    if (t < T_SEQ) {
#pragma unroll
      for (int r = 0; r < 4; r++)
        gds[w][((lane >> 4) << 2) + r][lane & 15] = a1x[r] + a1y[r];
    }
    bar_lgkm();  // (2) gds(layer1) visible

    // ---- act1 + publish h1(t) ----
    if (t < T_SEQ) {
      float gi = gds[0][row][c16] + b1v[0] + bf2f(xc[0]);
      float gf = gds[1][row][c16] + b1v[1] + bf2f(xc[1]);
      float gc = gds[2][row][c16] + b1v[2] + bf2f(xc[2]);
      float go = gds[3][row][c16] + b1v[3] + bf2f(xc[3]);
      float iv = fsigmoid(gi), fv = fsigmoid(gf), cd = ftanh(gc), ov = fsigmoid(go);
      float cold = cst1[row][c16];
      float cn = fv * cold + iv * cd;
      float hn = ov * ftanh(cn);
      if (mcur == 0) {
        cn = cold;
        hn = bf2f(*(const unsigned short*)(AhRowA + (((j0 + c16) * 2) ^ sw)));
      }
      cst1[row][c16] = cn;
      unsigned v1 = (((unsigned)(t + 1)) << 16) | f2bf(hn);
      unsigned int* d1 = ex + (size_t)(t & 1) * SLOT + (size_t)(b0 + row) * 512 + j0 + c16;
      asm volatile("global_store_dword %0, %1, off sc0 sc1" ::"v"(d1), "v"(v1) : "memory");
    }
    if (t == 0) {  // h2(-1) = 0, tag 1, slot 0 (layer2 bootstrap)
      unsigned v2 = 1u << 16;
      unsigned int* d2 = ex + (size_t)128 * 512 + (size_t)(b0 + row) * 512 + j0 + c16;
      asm volatile("global_store_dword %0, %1, off sc0 sc1" ::"v"(d2), "v"(v2) : "memory");
    }

    // ---- layer2 (step t-1): W2 chain over AhA, h2 stage issued around it ----
    if (t > 0) {
      unsigned doneB = 0;
      const unsigned int* bB = ex + (size_t)((t - 1) & 1) * SLOT + (size_t)128 * 512 +
                               (size_t)(b0 + row) * 512;
      stg_issue(bB, c16, pendB, doneB);  // h2(t-2) loads fly during W2 chain

      floatx4 a2x = (floatx4){0.f, 0.f, 0.f, 0.f};
      floatx4 a2y = (floatx4){0.f, 0.f, 0.f, 0.f};
#pragma unroll
      for (int kk = 0; kk < 16; kk += 2) {
        short8 a0 = *(const short8*)(AhA + frow * 1024 + ((kk * 64 + kbase) ^ fsw));
        short8 a1f = *(const short8*)(AhA + frow * 1024 + (((kk + 1) * 64 + kbase) ^ fsw));
        a2x = __builtin_amdgcn_mfma_f32_16x16x32_bf16(a0, wf2[kk], a2x, 0, 0, 0);
        a2y = __builtin_amdgcn_mfma_f32_16x16x32_bf16(a1f, wf2[kk + 1], a2y, 0, 0, 0);
      }

      stg_finish(bB, (unsigned)t, AhRowB, sw, c16, pendB, doneB);
      bar_lgkm();  // (3) AhB visible; act1's gds/AhA reads done before overwrite

      // chain2b: U2 fragments from LDS (swizzled): off critical path
#pragma unroll
      for (int kk = 0; kk < 16; kk += 2) {
        short8 a0 = *(const short8*)(AhB + frow * 1024 + ((kk * 64 + kbase) ^ fsw));
        short8 u0 = *(const short8*)(U2L + urow * 1024 + ((kk * 64 + kbase) ^ usw));
        short8 a1f = *(const short8*)(AhB + frow * 1024 + (((kk + 1) * 64 + kbase) ^ fsw));
        short8 u1 = *(const short8*)(U2L + urow * 1024 + (((kk + 1) * 64 + kbase) ^ usw));
        a2x = __builtin_amdgcn_mfma_f32_16x16x32_bf16(a0, u0, a2x, 0, 0, 0);
        a2y = __builtin_amdgcn_mfma_f32_16x16x32_bf16(a1f, u1, a2y, 0, 0, 0);
      }
#pragma unroll
      for (int r = 0; r < 4; r++)
        gds[w][((lane >> 4) << 2) + r][lane & 15] = a2x[r] + a2y[r];

      // issue stage A for t+1: peers published h1(t) at act1 (~700-1000cy ago ->
      // committed); act2+publish below covers the RT.
      if (t < T_SEQ) {
        const unsigned int* nA = ex + (size_t)(t & 1) * SLOT + (size_t)(b0 + row) * 512;
        doneA = 0;
        stg_issue(nA, c16, pendA, doneA);
      }
      bar_lgkm();  // (4) gds(layer2) visible

      {  // act2, publish h2(t-1), h2seq
        float gi = gds[0][row][c16] + b2v[0];
        float gf = gds[1][row][c16] + b2v[1];
        float gc = gds[2][row][c16] + b2v[2];
        float go = gds[3][row][c16] + b2v[3];
        float iv = fsigmoid(gi), fv = fsigmoid(gf), cd = ftanh(gc), ov = fsigmoid(go);
        float cold = cst2[row][c16];
        float cn = fv * cold + iv * cd;
        float hn = ov * ftanh(cn);
        if (mprev == 0) {
          cn = cold;
          hn = bf2f(*(const unsigned short*)(AhRowB + (((j0 + c16) * 2) ^ sw)));
        }
        cst2[row][c16] = cn;
        unsigned short hb = f2bf(hn);
        if (t < T_SEQ) {
          unsigned v2 = (((unsigned)(t + 1)) << 16) | hb;
          unsigned int* d2 = ex + (size_t)(t & 1) * SLOT + (size_t)128 * 512 +
                             (size_t)(b0 + row) * 512 + j0 + c16;
          asm volatile("global_store_dword %0, %1, off sc0 sc1" ::"v"(d2), "v"(v2) : "memory");
        }
        h2seq[((size_t)(b0 + row) * T_SEQ + (t - 1)) * HID + j0 + c16] = hb;
      }
    } else {
      // t == 0: no layer2 yet; issue stage A for t=1 at the iteration end
      const unsigned int* nA = ex + (size_t)(t & 1) * SLOT + (size_t)(b0 + row) * 512;
      doneA = 0;
      stg_issue(nA, c16, pendA, doneA);
    }
    mprev = mcur;
    mcur = (t + 1 < T_SEQ) ? widp[t + 1] : 0;
#pragma unroll
    for (int g = 0; g < 4; g++) xc[g] = xn[g];
  }
}

// ---------- dense (512->96) + softmax, MFMA ----------
__global__ __launch_bounds__(256) void dense_softmax(const unsigned short* __restrict__ h2,
                                                     const unsigned short* __restrict__ Wdt,
                                                     const float* __restrict__ bd,
                                                     float* __restrict__ out) {
  int m0 = blockIdx.x * 64;
  int tid = threadIdx.x, lane = tid & 63, w = tid >> 6;
  __shared__ __align__(16) char As[64 * ASTR];
  __shared__ __align__(16) char Bs[96 * ASTR];
  floatx4 acc[6];
#pragma unroll
  for (int i = 0; i < 6; i++) acc[i] = (floatx4){0.f, 0.f, 0.f, 0.f};
  for (int k0 = 0; k0 < 512; k0 += 32) {
    {
      int row = tid >> 2, part = tid & 3;
      short8 v = *(const short8*)(h2 + (size_t)(m0 + row) * 512 + k0 + part * 8);
      *(short8*)(As + row * ASTR + part * 16) = v;
    }
    for (int u = tid; u < 96 * 4; u += 256) {
      int col = u >> 2, part = u & 3;
      short8 v = *(const short8*)(Wdt + (size_t)col * 512 + k0 + part * 8);
      *(short8*)(Bs + col * ASTR + part * 16) = v;
    }
    __syncthreads();
    int arow = w * 16 + (lane & 15);
    short8 a = *(const short8*)(As + arow * ASTR + (lane >> 4) * 16);
#pragma unroll
    for (int nc = 0; nc < 6; nc++) {
      int bcol = nc * 16 + (lane & 15);
      short8 b = *(const short8*)(Bs + bcol * ASTR + (lane >> 4) * 16);
      acc[nc] = __builtin_amdgcn_mfma_f32_16x16x32_bf16(a, b, acc[nc], 0, 0, 0);
    }
    __syncthreads();
  }
  float bv[6];
#pragma unroll
  for (int nc = 0; nc < 6; nc++) bv[nc] = bd[nc * 16 + (lane & 15)];
#pragma unroll
  for (int r = 0; r < 4; r++) {
    float v[6];
    float mx = -1e30f;
#pragma unroll
    for (int nc = 0; nc < 6; nc++) {
      v[nc] = acc[nc][r] + bv[nc];
      mx = fmaxf(mx, v[nc]);
    }
#pragma unroll
    for (int d = 1; d < 16; d <<= 1) mx = fmaxf(mx, __shfl_xor(mx, d));
    float s = 0.f;
#pragma unroll
    for (int nc = 0; nc < 6; nc++) {
      v[nc] = __expf(v[nc] - mx);
      s += v[nc];
    }
#pragma unroll
    for (int d = 1; d < 16; d <<= 1) s += __shfl_xor(s, d);
    float inv = 1.0f / s;
    int rr = m0 + w * 16 + ((lane >> 4) << 2) + r;
#pragma unroll
    for (int nc = 0; nc < 6; nc++) out[(size_t)rr * 96 + nc * 16 + (lane & 15)] = v[nc] * inv;
  }
}

extern "C" void kernel_launch(void* const* d_in, const int* in_sizes, int n_in,
                              void* d_out, int out_size, void* d_ws, size_t ws_size,
                              hipStream_t stream) {
  (void)in_sizes; (void)n_in; (void)out_size; (void)ws_size;
  const int* word_ids = (const int*)d_in[0];
  const int* pred = (const int*)d_in[1];
  const float* emb = (const float*)d_in[2];
  const float* W1 = (const float*)d_in[3];
  const float* U1 = (const float*)d_in[4];
  const float* b1 = (const float*)d_in[5];
  const float* W2 = (const float*)d_in[6];
  const float* U2 = (const float*)d_in[7];
  const float* b2 = (const float*)d_in[8];
  const float* Wd = (const float*)d_in[9];
  const float* bd = (const float*)d_in[10];
  float* out = (float*)d_out;

  const size_t EXBYTES = (size_t)2 * 2 * 128 * 512 * 4;  // 1 MB depth-2 ring

  char* p = (char*)d_ws;
  unsigned short* xg = (unsigned short*)p;   p += (size_t)32768 * 2048 * 2;  // 128MB
  unsigned short* h2s = (unsigned short*)p;  p += (size_t)32768 * 512 * 2;   // 32MB
  unsigned int* ex = (unsigned int*)p;       p += EXBYTES;
  unsigned short* Ut1 = (unsigned short*)p;  p += (size_t)2048 * 512 * 2;
  unsigned short* Ut2 = (unsigned short*)p;  p += (size_t)2048 * 512 * 2;
  unsigned short* Wt1 = (unsigned short*)p;  p += (size_t)2048 * 320 * 2;
  unsigned short* Wt2 = (unsigned short*)p;  p += (size_t)2048 * 512 * 2;
  unsigned short* Wdt = (unsigned short*)p;  p += (size_t)96 * 512 * 2;

  // clear exchange ring every launch: kills cross-replay stale-tag race
  hipMemsetAsync(ex, 0, EXBYTES, stream);

  hipLaunchKernelGGL(transpose_bf16, dim3(64, 16), dim3(256), 0, stream, U1, Ut1, 512, 2048, 512);
  hipLaunchKernelGGL(transpose_bf16, dim3(64, 16), dim3(256), 0, stream, U2, Ut2, 512, 2048, 512);
  hipLaunchKernelGGL(transpose_bf16, dim3(64, 10), dim3(256), 0, stream, W1, Wt1, 301, 2048, 320);
  hipLaunchKernelGGL(transpose_bf16, dim3(64, 16), dim3(256), 0, stream, W2, Wt2, 512, 2048, 512);
  hipLaunchKernelGGL(transpose_bf16, dim3(3, 16), dim3(256), 0, stream, Wd, Wdt, 512, 96, 512);

  hipLaunchKernelGGL(gemm_xg1, dim3(512), dim3(256), 0, stream,
                     emb, word_ids, pred, Wt1, xg);
  hipLaunchKernelGGL(lstm_merged, dim3(256), dim3(256), 0, stream,
                     xg, Ut1, b1, Wt2, Ut2, b2, word_ids, ex, h2s);
  hipLaunchKernelGGL(dense_softmax, dim3(512), dim3(256), 0, stream, h2s, Wdt, bd, out);
}

// Round 18
// 1290.429 us; speedup vs baseline: 1.2214x; 1.0570x over previous
//
#include <hip/hip_runtime.h>
#include <hip/hip_bf16.h>

#define T_SEQ 256
#define HID 512
#define G4 2048
#define ASTR 80  // padded LDS row stride (bytes) for 64B rows in GEMM kernels

typedef __attribute__((ext_vector_type(8))) short short8;
typedef __attribute__((ext_vector_type(4))) float floatx4;
typedef __attribute__((ext_vector_type(4))) int intx4;

__device__ inline unsigned short f2bf(float f) {
  union { __hip_bfloat16 h; unsigned short u; } cv;
  cv.h = __float2bfloat16(f);
  return cv.u;
}
__device__ inline float bf2f(unsigned short u) {
  union { unsigned short u; __hip_bfloat16 h; } cv;
  cv.u = u;
  return __bfloat162float(cv.h);
}
__device__ inline float fsigmoid(float x) {
  return __builtin_amdgcn_rcpf(1.0f + __expf(-x));
}
__device__ inline float ftanh(float x) {
  float e = __expf(2.0f * x);
  return 1.0f - 2.0f * __builtin_amdgcn_rcpf(e + 1.0f);
}

// barrier with LDS-only drain (publish stores must NOT be waited at barriers)
__device__ __forceinline__ void bar_lgkm() {
  asm volatile("s_waitcnt lgkmcnt(0)\n\ts_barrier" ::: "memory");
}

// ---------- transpose+convert: src [K][N] f32 -> dst [N][Kpad] bf16 (zero pad) ----------
__global__ __launch_bounds__(256) void transpose_bf16(const float* __restrict__ src,
                                                      unsigned short* __restrict__ dst,
                                                      int K, int N, int Kpad) {
  __shared__ float tile[32][33];
  int n0 = blockIdx.x * 32, k0 = blockIdx.y * 32;
  int tx = threadIdx.x & 31, ty = threadIdx.x >> 5;  // 32 x 8
#pragma unroll
  for (int i = 0; i < 32; i += 8) {
    int k = k0 + ty + i, n = n0 + tx;
    tile[ty + i][tx] = (k < K) ? src[(size_t)k * N + n] : 0.0f;
  }
  __syncthreads();
#pragma unroll
  for (int i = 0; i < 32; i += 8) {
    int n = n0 + ty + i, k = k0 + tx;
    dst[(size_t)n * Kpad + k] = f2bf(tile[tx][ty + i]);
  }
}

// ---------- xg1 GEMM: gather each emb row ONCE into LDS, loop over all N ----------
__global__ __launch_bounds__(256) void gemm_xg1(const float* __restrict__ emb,
                                                const int* __restrict__ wid,
                                                const int* __restrict__ pred,
                                                const unsigned short* __restrict__ Bt,
                                                unsigned short* __restrict__ C) {
  int m0 = blockIdx.x * 64;
  int tid = threadIdx.x, lane = tid & 63, w = tid >> 6;
  __shared__ __align__(16) short As[64][328];
  __shared__ __align__(16) short Bs[2][64][40];
  {
    int grow = tid >> 2, gpart = tid & 3;
    int wrow = wid[m0 + grow];
    float pflag = (float)pred[m0 + grow];
    const float* erow = emb + (size_t)wrow * 300;
#pragma unroll
    for (int i = 0; i < 10; i++) {
      int c0 = gpart * 80 + i * 8;
      float f[8];
      if (c0 + 8 <= 300) {
        float4 x0 = *(const float4*)(erow + c0);
        float4 x1 = *(const float4*)(erow + c0 + 4);
        f[0] = x0.x; f[1] = x0.y; f[2] = x0.z; f[3] = x0.w;
        f[4] = x1.x; f[5] = x1.y; f[6] = x1.z; f[7] = x1.w;
      } else {
#pragma unroll
        for (int j = 0; j < 8; j++) {
          int k = c0 + j;
          f[j] = (k < 300) ? erow[k] : ((k == 300) ? pflag : 0.0f);
        }
      }
      short8 v;
#pragma unroll
      for (int j = 0; j < 8; j++) v[j] = (short)f2bf(f[j]);
      *(short8*)&As[grow][c0] = v;
    }
  }
  int brow = tid >> 2, bpart = tid & 3;
  for (int n0 = 0; n0 < 2048; n0 += 64) {
    *(short8*)&Bs[0][brow][bpart * 8] =
        *(const short8*)(Bt + (size_t)(n0 + brow) * 320 + bpart * 8);
    bar_lgkm();
    floatx4 acc[4];
#pragma unroll
    for (int i = 0; i < 4; i++) acc[i] = (floatx4){0.f, 0.f, 0.f, 0.f};
#pragma unroll
    for (int ks = 0; ks < 10; ks++) {
      if (ks < 9)
        *(short8*)&Bs[(ks + 1) & 1][brow][bpart * 8] =
            *(const short8*)(Bt + (size_t)(n0 + brow) * 320 + (ks + 1) * 32 + bpart * 8);
      short8 afr = *(const short8*)&As[w * 16 + (lane & 15)][ks * 32 + (lane >> 4) * 8];
#pragma unroll
      for (int nc = 0; nc < 4; nc++) {
        short8 bfr = *(const short8*)&Bs[ks & 1][nc * 16 + (lane & 15)][(lane >> 4) * 8];
        acc[nc] = __builtin_amdgcn_mfma_f32_16x16x32_bf16(afr, bfr, acc[nc], 0, 0, 0);
      }
      bar_lgkm();
    }
#pragma unroll
    for (int nc = 0; nc < 4; nc++)
#pragma unroll
      for (int r = 0; r < 4; r++) {
        int rr = m0 + w * 16 + ((lane >> 4) << 2) + r;
        int cc = n0 + nc * 16 + (lane & 15);
        C[(size_t)rr * G4 + cc] = f2bf(acc[nc][r]);
      }
  }
}

// ---------- tagged exchange (IC-only: sc0 sc1 is no-allocate; NEVER poll via L2 -
// stale allocated lines are not invalidated cross-XCD -> r8 hang) ----------
// Thread owns 32 cols of one 512-col row: granule i (0..7) = 4 tagged u32 at cols
// 8*c16 + 128*(i>>1) + 4*(i&1). Valid when all 4 high-16 tags == want.
// COUNTED-VMCNT (r18): first check waits vmcnt(W) where W = #VMEM ops issued after the
// stage's loads (VMEM retires in issue order -> all loads landed; store acks NOT drained).
// Under-count safety: in-flight registers hold stale tag (t-1, or 0 at first use via
// zero-init) != t -> the retry loop (vmcnt(0)) re-issues. Over-count impossible.
__device__ __forceinline__ void stg_issue(const unsigned int* rowbase, int c16,
                                          intx4 (&v)[8], unsigned done) {
#pragma unroll
  for (int i = 0; i < 8; i++) {
    if (!(done & (1u << i))) {
      const unsigned int* p = rowbase + 8 * c16 + 128 * (i >> 1) + 4 * (i & 1);
      asm volatile("global_load_dwordx4 %0, %1, off sc0 sc1" : "=v"(v[i]) : "v"(p) : "memory");
    }
  }
}
template <int W>
__device__ __forceinline__ void stg_checkw(unsigned want, char* AhRow, int sw, int c16,
                                           intx4 (&v)[8], unsigned& done) {
  if constexpr (W == 0) asm volatile("s_waitcnt vmcnt(0)" ::: "memory");
  else if constexpr (W == 1) asm volatile("s_waitcnt vmcnt(1)" ::: "memory");
  else asm volatile("s_waitcnt vmcnt(2)" ::: "memory");
#pragma unroll
  for (int i = 0; i < 8; i++) {
    if (!(done & (1u << i))) {
      intx4 a = v[i];
      unsigned u0 = (unsigned)a.x, u1 = (unsigned)a.y, u2 = (unsigned)a.z, u3 = (unsigned)a.w;
      bool ok = ((u0 >> 16) == want) & ((u1 >> 16) == want) & ((u2 >> 16) == want) &
                ((u3 >> 16) == want);
      if (ok) {
        uint2 pp;
        pp.x = (u0 & 0xffffu) | (u1 << 16);
        pp.y = (u2 & 0xffffu) | (u3 << 16);
        int s = c16 + 16 * (i >> 1);
        *(uint2*)(AhRow + ((s * 16) ^ sw) + (i & 1) * 8) = pp;
        done |= (1u << i);
      }
    }
  }
}
template <int FW>
__device__ __forceinline__ void stg_finishw(const unsigned int* rowbase, unsigned want,
                                            char* AhRow, int sw, int c16,
                                            intx4 (&v)[8], unsigned& done) {
  stg_checkw<FW>(want, AhRow, sw, c16, v, done);
  while (done != 0xFFu) {
    __builtin_amdgcn_s_sleep(1);
    stg_issue(rowbase, c16, v, done);
    stg_checkw<0>(want, AhRow, sw, c16, v, done);
  }
}

// ---------- merged persistent dual-layer masked LSTM: 256 blocks x 256 threads ----------
// r14 structure (empirical optimum) + r18 counted-vmcnt scheduling:
//  - checkA = vmcnt(2): exactly publish-h2 + h2seq stores issued after issueA (mask
//    prefetch moved to top so it precedes issueA).
//  - issueB moved before act1 (right after bar(2)): +~1000cy flight; checkB = vmcnt(1)
//    (only publish-h1 store issued after it).
//  - pendA/pendB zero-initialized: first-use in-flight registers hold tag 0 != 1.
// Everything else r14-identical.
__global__ __launch_bounds__(256, 1) __attribute__((amdgpu_waves_per_eu(1, 1)))
void lstm_merged(
    const unsigned short* __restrict__ xg1,
    const unsigned short* __restrict__ Ut1, const float* __restrict__ b1,
    const unsigned short* __restrict__ Wt2, const unsigned short* __restrict__ Ut2,
    const float* __restrict__ b2, const int* __restrict__ wid,
    unsigned int* ex, unsigned short* h2seq) {
  const int blk = blockIdx.x;
  const int bgrp = blk & 7, jblk = blk >> 3;
  const int b0 = bgrp * 16, j0 = jblk * 16;
  const int tid = threadIdx.x, lane = tid & 63, w = tid >> 6;  // 4 waves = 4 gates

  __shared__ __align__(16) char AhA[16 * 1024];  // h1(t-1) bf16 [16][512], swizzled
  __shared__ __align__(16) char AhB[16 * 1024];  // h2(t-2)
  __shared__ __align__(16) char U2L[64 * 1024];  // U2 slice [64 ucols][512 k], swizzled
  __shared__ float gds[4][16][16];               // gate pre-acts, reused by both layers
  __shared__ float cst1[16][16];
  __shared__ float cst2[16][16];

  const int row = tid >> 4, c16 = tid & 15;  // act + stage mapping
  const int sw = (row & 7) << 4;
  char* AhRowA = AhA + row * 1024;
  char* AhRowB = AhB + row * 1024;
  const int ucol = w * 512 + j0 + (lane & 15);
  const int* widp = wid + (size_t)(b0 + row) * T_SEQ;

  // register weights: U1 + W2 only (128 VGPR); U2 lives in LDS
  short8 uf1[16], wf2[16];
  {
    const unsigned short* p1 = Ut1 + (size_t)ucol * 512 + ((lane >> 4) * 8);
    const unsigned short* p2 = Wt2 + (size_t)ucol * 512 + ((lane >> 4) * 8);
#pragma unroll
    for (int kk = 0; kk < 16; kk++) {
      uf1[kk] = *(const short8*)(p1 + kk * 32);
      wf2[kk] = *(const short8*)(p2 + kk * 32);
    }
  }
  // U2 slice -> LDS (64 rows x 1024B, XOR-swizzled like Ah tiles)
  for (int i = tid; i < 4096; i += 256) {
    int r = i >> 6, seg = i & 63;
    short8 v = *(const short8*)(Ut2 + (size_t)((r >> 4) * 512 + j0 + (r & 15)) * 512 + seg * 8);
    *(short8*)(U2L + r * 1024 + ((seg * 16) ^ ((r & 7) << 4))) = v;
  }
  float b1v[4], b2v[4];
#pragma unroll
  for (int g = 0; g < 4; g++) {
    b1v[g] = b1[g * 512 + j0 + c16];
    b2v[g] = b2[g * 512 + j0 + c16];
  }
  cst1[row][c16] = 0.0f;
  cst2[row][c16] = 0.0f;
  {
    short8 z = {0, 0, 0, 0, 0, 0, 0, 0};
    for (int i = tid; i < 1024; i += 256) {
      *(short8*)(AhA + i * 16) = z;
      *(short8*)(AhB + i * 16) = z;
    }
  }
  __syncthreads();

  const unsigned short* xgrow = xg1 + (size_t)(b0 + row) * T_SEQ * G4 + j0 + c16;
  unsigned short xc[4], xn[4];
#pragma unroll
  for (int g = 0; g < 4; g++) { xc[g] = xgrow[g * 512]; xn[g] = 0; }
  int mcur = widp[0];
  int mprev = 0;

  const size_t SLOT = (size_t)2 * 128 * 512;  // u32 per ring slot
  const int frow = lane & 15, kbase = (lane >> 4) * 16, fsw = (frow & 7) << 4;
  const int urow = w * 16 + (lane & 15);
  const int usw = (urow & 7) << 4;

  intx4 pendA[8], pendB[8];
#pragma unroll
  for (int i = 0; i < 8; i++) {  // zero-init: first-use stale tags = 0 (never match)
    pendA[i] = (intx4){0, 0, 0, 0};
    pendB[i] = (intx4){0, 0, 0, 0};
  }
  unsigned doneA = 0xFFu;  // nothing staged for t=0

  for (int t = 0; t <= T_SEQ; t++) {
    // ---- finish stage A: h1(t-1). vmcnt(2): the 2 act2 stores may stay in flight ----
    if (t > 0) {
      const unsigned int* bA = ex + (size_t)((t - 1) & 1) * SLOT + (size_t)(b0 + row) * 512;
      stg_finishw<2>(bA, (unsigned)t, AhRowA, sw, c16, pendA, doneA);
    }
    // prefetch next step's xg + mask (both BEFORE issueA -> excluded from its count)
    int mnext = 0;
    if (t + 1 < T_SEQ) {
      const unsigned short* xr = xgrow + (size_t)(t + 1) * G4;
#pragma unroll
      for (int g = 0; g < 4; g++) xn[g] = xr[g * 512];
      mnext = widp[t + 1];
    }
    bar_lgkm();  // (1) AhA staged & visible

    // ---- layer1 chain: U1 over AhA, 2 interleaved accumulators ----
    floatx4 a1x = (floatx4){0.f, 0.f, 0.f, 0.f};
    floatx4 a1y = (floatx4){0.f, 0.f, 0.f, 0.f};
#pragma unroll
    for (int kk = 0; kk < 16; kk += 2) {
      short8 a0 = *(const short8*)(AhA + frow * 1024 + ((kk * 64 + kbase) ^ fsw));
      short8 a1f = *(const short8*)(AhA + frow * 1024 + (((kk + 1) * 64 + kbase) ^ fsw));
      a1x = __builtin_amdgcn_mfma_f32_16x16x32_bf16(a0, uf1[kk], a1x, 0, 0, 0);
      a1y = __builtin_amdgcn_mfma_f32_16x16x32_bf16(a1f, uf1[kk + 1], a1y, 0, 0, 0);
    }
    if (t < T_SEQ) {
#pragma unroll
      for (int r = 0; r < 4; r++)
        gds[w][((lane >> 4) << 2) + r][lane & 15] = a1x[r] + a1y[r];
    }
    bar_lgkm();  // (2) gds(layer1) visible

    // ---- issue stage B EARLY (before act1's publish): h2(t-2) loads get the whole
    //      act1+chain2a to fly; only publish-h1 is issued after -> checkB = vmcnt(1) ----
    unsigned doneB = 0xFFu;
    if (t > 0) {
      const unsigned int* bB = ex + (size_t)((t - 1) & 1) * SLOT + (size_t)128 * 512 +
                               (size_t)(b0 + row) * 512;
      doneB = 0;
      stg_issue(bB, c16, pendB, doneB);
    }

    // ---- act1 + publish h1(t) ----
    if (t < T_SEQ) {
      float gi = gds[0][row][c16] + b1v[0] + bf2f(xc[0]);
      float gf = gds[1][row][c16] + b1v[1] + bf2f(xc[1]);
      float gc = gds[2][row][c16] + b1v[2] + bf2f(xc[2]);
      float go = gds[3][row][c16] + b1v[3] + bf2f(xc[3]);
      float iv = fsigmoid(gi), fv = fsigmoid(gf), cd = ftanh(gc), ov = fsigmoid(go);
      float cold = cst1[row][c16];
      float cn = fv * cold + iv * cd;
      float hn = ov * ftanh(cn);
      if (mcur == 0) {
        cn = cold;
        hn = bf2f(*(const unsigned short*)(AhRowA + (((j0 + c16) * 2) ^ sw)));
      }
      cst1[row][c16] = cn;
      unsigned v1 = (((unsigned)(t + 1)) << 16) | f2bf(hn);
      unsigned int* d1 = ex + (size_t)(t & 1) * SLOT + (size_t)(b0 + row) * 512 + j0 + c16;
      asm volatile("global_store_dword %0, %1, off sc0 sc1" ::"v"(d1), "v"(v1) : "memory");
    }
    if (t == 0) {  // h2(-1) = 0, tag 1, slot 0 (layer2 bootstrap)
      unsigned v2 = 1u << 16;
      unsigned int* d2 = ex + (size_t)128 * 512 + (size_t)(b0 + row) * 512 + j0 + c16;
      asm volatile("global_store_dword %0, %1, off sc0 sc1" ::"v"(d2), "v"(v2) : "memory");
    }

    // ---- layer2 (step t-1): W2 chain over AhA; finish B after it ----
    if (t > 0) {
      floatx4 a2x = (floatx4){0.f, 0.f, 0.f, 0.f};
      floatx4 a2y = (floatx4){0.f, 0.f, 0.f, 0.f};
#pragma unroll
      for (int kk = 0; kk < 16; kk += 2) {
        short8 a0 = *(const short8*)(AhA + frow * 1024 + ((kk * 64 + kbase) ^ fsw));
        short8 a1f = *(const short8*)(AhA + frow * 1024 + (((kk + 1) * 64 + kbase) ^ fsw));
        a2x = __builtin_amdgcn_mfma_f32_16x16x32_bf16(a0, wf2[kk], a2x, 0, 0, 0);
        a2y = __builtin_amdgcn_mfma_f32_16x16x32_bf16(a1f, wf2[kk + 1], a2y, 0, 0, 0);
      }

      const unsigned int* bB = ex + (size_t)((t - 1) & 1) * SLOT + (size_t)128 * 512 +
                               (size_t)(b0 + row) * 512;
      stg_finishw<1>(bB, (unsigned)t, AhRowB, sw, c16, pendB, doneB);
      bar_lgkm();  // (3) AhB visible; act1's gds/AhA reads done before overwrite

      // chain2b: U2 fragments from LDS (swizzled): off critical path
#pragma unroll
      for (int kk = 0; kk < 16; kk += 2) {
        short8 a0 = *(const short8*)(AhB + frow * 1024 + ((kk * 64 + kbase) ^ fsw));
        short8 u0 = *(const short8*)(U2L + urow * 1024 + ((kk * 64 + kbase) ^ usw));
        short8 a1f = *(const short8*)(AhB + frow * 1024 + (((kk + 1) * 64 + kbase) ^ fsw));
        short8 u1 = *(const short8*)(U2L + urow * 1024 + (((kk + 1) * 64 + kbase) ^ usw));
        a2x = __builtin_amdgcn_mfma_f32_16x16x32_bf16(a0, u0, a2x, 0, 0, 0);
        a2y = __builtin_amdgcn_mfma_f32_16x16x32_bf16(a1f, u1, a2y, 0, 0, 0);
      }
#pragma unroll
      for (int r = 0; r < 4; r++)
        gds[w][((lane >> 4) << 2) + r][lane & 15] = a2x[r] + a2y[r];

      // issue stage A for t+1: peers published h1(t) at act1 (~700-1000cy ago ->
      // committed); act2+publish below covers the RT.
      if (t < T_SEQ) {
        const unsigned int* nA = ex + (size_t)(t & 1) * SLOT + (size_t)(b0 + row) * 512;
        doneA = 0;
        stg_issue(nA, c16, pendA, doneA);
      }
      bar_lgkm();  // (4) gds(layer2) visible

      {  // act2, publish h2(t-1), h2seq  (exactly 2 VMEM stores after issueA)
        float gi = gds[0][row][c16] + b2v[0];
        float gf = gds[1][row][c16] + b2v[1];
        float gc = gds[2][row][c16] + b2v[2];
        float go = gds[3][row][c16] + b2v[3];
        float iv = fsigmoid(gi), fv = fsigmoid(gf), cd = ftanh(gc), ov = fsigmoid(go);
        float cold = cst2[row][c16];
        float cn = fv * cold + iv * cd;
        float hn = ov * ftanh(cn);
        if (mprev == 0) {
          cn = cold;
          hn = bf2f(*(const unsigned short*)(AhRowB + (((j0 + c16) * 2) ^ sw)));
        }
        cst2[row][c16] = cn;
        unsigned short hb = f2bf(hn);
        if (t < T_SEQ) {
          unsigned v2 = (((unsigned)(t + 1)) << 16) | hb;
          unsigned int* d2 = ex + (size_t)(t & 1) * SLOT + (size_t)128 * 512 +
                             (size_t)(b0 + row) * 512 + j0 + c16;
          asm volatile("global_store_dword %0, %1, off sc0 sc1" ::"v"(d2), "v"(v2) : "memory");
        }
        h2seq[((size_t)(b0 + row) * T_SEQ + (t - 1)) * HID + j0 + c16] = hb;
      }
    } else {
      // t == 0: no layer2 yet; issue stage A for t=1 at the iteration end
      const unsigned int* nA = ex + (size_t)(t & 1) * SLOT + (size_t)(b0 + row) * 512;
      doneA = 0;
      stg_issue(nA, c16, pendA, doneA);
    }
    mprev = mcur;
    mcur = mnext;
#pragma unroll
    for (int g = 0; g < 4; g++) xc[g] = xn[g];
  }
}

// ---------- dense (512->96) + softmax, MFMA ----------
__global__ __launch_bounds__(256) void dense_softmax(const unsigned short* __restrict__ h2,
                                                     const unsigned short* __restrict__ Wdt,
                                                     const float* __restrict__ bd,
                                                     float* __restrict__ out) {
  int m0 = blockIdx.x * 64;
  int tid = threadIdx.x, lane = tid & 63, w = tid >> 6;
  __shared__ __align__(16) char As[64 * ASTR];
  __shared__ __align__(16) char Bs[96 * ASTR];
  floatx4 acc[6];
#pragma unroll
  for (int i = 0; i < 6; i++) acc[i] = (floatx4){0.f, 0.f, 0.f, 0.f};
  for (int k0 = 0; k0 < 512; k0 += 32) {
    {
      int row = tid >> 2, part = tid & 3;
      short8 v = *(const short8*)(h2 + (size_t)(m0 + row) * 512 + k0 + part * 8);
      *(short8*)(As + row * ASTR + part * 16) = v;
    }
    for (int u = tid; u < 96 * 4; u += 256) {
      int col = u >> 2, part = u & 3;
      short8 v = *(const short8*)(Wdt + (size_t)col * 512 + k0 + part * 8);
      *(short8*)(Bs + col * ASTR + part * 16) = v;
    }
    __syncthreads();
    int arow = w * 16 + (lane & 15);
    short8 a = *(const short8*)(As + arow * ASTR + (lane >> 4) * 16);
#pragma unroll
    for (int nc = 0; nc < 6; nc++) {
      int bcol = nc * 16 + (lane & 15);
      short8 b = *(const short8*)(Bs + bcol * ASTR + (lane >> 4) * 16);
      acc[nc] = __builtin_amdgcn_mfma_f32_16x16x32_bf16(a, b, acc[nc], 0, 0, 0);
    }
    __syncthreads();
  }
  float bv[6];
#pragma unroll
  for (int nc = 0; nc < 6; nc++) bv[nc] = bd[nc * 16 + (lane & 15)];
#pragma unroll
  for (int r = 0; r < 4; r++) {
    float v[6];
    float mx = -1e30f;
#pragma unroll
    for (int nc = 0; nc < 6; nc++) {
      v[nc] = acc[nc][r] + bv[nc];
      mx = fmaxf(mx, v[nc]);
    }
#pragma unroll
    for (int d = 1; d < 16; d <<= 1) mx = fmaxf(mx, __shfl_xor(mx, d));
    float s = 0.f;
#pragma unroll
    for (int nc = 0; nc < 6; nc++) {
      v[nc] = __expf(v[nc] - mx);
      s += v[nc];
    }
#pragma unroll
    for (int d = 1; d < 16; d <<= 1) s += __shfl_xor(s, d);
    float inv = 1.0f / s;
    int rr = m0 + w * 16 + ((lane >> 4) << 2) + r;
#pragma unroll
    for (int nc = 0; nc < 6; nc++) out[(size_t)rr * 96 + nc * 16 + (lane & 15)] = v[nc] * inv;
  }
}

extern "C" void kernel_launch(void* const* d_in, const int* in_sizes, int n_in,
                              void* d_out, int out_size, void* d_ws, size_t ws_size,
                              hipStream_t stream) {
  (void)in_sizes; (void)n_in; (void)out_size; (void)ws_size;
  const int* word_ids = (const int*)d_in[0];
  const int* pred = (const int*)d_in[1];
  const float* emb = (const float*)d_in[2];
  const float* W1 = (const float*)d_in[3];
  const float* U1 = (const float*)d_in[4];
  const float* b1 = (const float*)d_in[5];
  const float* W2 = (const float*)d_in[6];
  const float* U2 = (const float*)d_in[7];
  const float* b2 = (const float*)d_in[8];
  const float* Wd = (const float*)d_in[9];
  const float* bd = (const float*)d_in[10];
  float* out = (float*)d_out;

  const size_t EXBYTES = (size_t)2 * 2 * 128 * 512 * 4;  // 1 MB depth-2 ring

  char* p = (char*)d_ws;
  unsigned short* xg = (unsigned short*)p;   p += (size_t)32768 * 2048 * 2;  // 128MB
  unsigned short* h2s = (unsigned short*)p;  p += (size_t)32768 * 512 * 2;   // 32MB
  unsigned int* ex = (unsigned int*)p;       p += EXBYTES;
  unsigned short* Ut1 = (unsigned short*)p;  p += (size_t)2048 * 512 * 2;
  unsigned short* Ut2 = (unsigned short*)p;  p += (size_t)2048 * 512 * 2;
  unsigned short* Wt1 = (unsigned short*)p;  p += (size_t)2048 * 320 * 2;
  unsigned short* Wt2 = (unsigned short*)p;  p += (size_t)2048 * 512 * 2;
  unsigned short* Wdt = (unsigned short*)p;  p += (size_t)96 * 512 * 2;

  // clear exchange ring every launch: kills cross-replay stale-tag race
  hipMemsetAsync(ex, 0, EXBYTES, stream);

  hipLaunchKernelGGL(transpose_bf16, dim3(64, 16), dim3(256), 0, stream, U1, Ut1, 512, 2048, 512);
  hipLaunchKernelGGL(transpose_bf16, dim3(64, 16), dim3(256), 0, stream, U2, Ut2, 512, 2048, 512);
  hipLaunchKernelGGL(transpose_bf16, dim3(64, 10), dim3(256), 0, stream, W1, Wt1, 301, 2048, 320);
  hipLaunchKernelGGL(transpose_bf16, dim3(64, 16), dim3(256), 0, stream, W2, Wt2, 512, 2048, 512);
  hipLaunchKernelGGL(transpose_bf16, dim3(3, 16), dim3(256), 0, stream, Wd, Wdt, 512, 96, 512);

  hipLaunchKernelGGL(gemm_xg1, dim3(512), dim3(256), 0, stream,
                     emb, word_ids, pred, Wt1, xg);
  hipLaunchKernelGGL(lstm_merged, dim3(256), dim3(256), 0, stream,
                     xg, Ut1, b1, Wt2, Ut2, b2, word_ids, ex, h2s);
  hipLaunchKernelGGL(dense_softmax, dim3(512), dim3(256), 0, stream, h2s, Wdt, bd, out);
}